// Round 7
// baseline (234.655 us; speedup 1.0000x reference)
//
#include <hip/hip_runtime.h>
#include <hip/hip_bf16.h>

// S=64, C=27. DOTLEN = 8640 = 2160 float4/row; state = 320; comb = 640; hidden = 64.

__device__ __forceinline__ float ag_load(const float* p) {
    return __hip_atomic_load(p, __ATOMIC_RELAXED, __HIP_MEMORY_SCOPE_AGENT);
}
__device__ __forceinline__ void ag_store(float* p, float v) {
    __hip_atomic_store(p, v, __ATOMIC_RELAXED, __HIP_MEMORY_SCOPE_AGENT);
}

__device__ __forceinline__ float wave_reduce_sum(float v) {
    v += __shfl_xor(v, 32, 64);
    v += __shfl_xor(v, 16, 64);
    v += __shfl_xor(v, 8, 64);
    v += __shfl_xor(v, 4, 64);
    v += __shfl_xor(v, 2, 64);
    v += __shfl_xor(v, 1, 64);
    return v;
}

// Shared two-layer MLP tail (R1-proven): comb[640] in LDS -> h[64] -> 320 outs.
// outp[i] = comb[i] + W2[i,:] @ relu(W1 @ comb + b1) + b2[i]
__device__ __forceinline__ void mlp_core(int tid,
                                         const float* __restrict__ W1,
                                         const float* __restrict__ b1,
                                         const float* __restrict__ W2,
                                         const float* __restrict__ b2,
                                         const float* __restrict__ base,  // residual source [320]
                                         float* __restrict__ outp,
                                         float* comb, float* h, bool agstore) {
    __syncthreads();
    const int wv = tid >> 6, lane = tid & 63;
    for (int k = wv * 16; k < wv * 16 + 16; ++k) {
        float acc = 0.f;
        #pragma unroll
        for (int j = lane; j < 640; j += 64)
            acc = fmaf(W1[k * 640 + j], comb[j], acc);
        acc = wave_reduce_sum(acc);
        if (lane == 0) h[k] = fmaxf(acc + b1[k], 0.f);
    }
    __syncthreads();
    for (int i = tid; i < 320; i += 256) {
        const float4* __restrict__ w = reinterpret_cast<const float4*>(W2 + (size_t)i * 64);
        float acc = 0.f;
        #pragma unroll
        for (int j4 = 0; j4 < 16; ++j4) {
            float4 ww = w[j4];
            acc = fmaf(ww.x, h[4 * j4 + 0], acc);
            acc = fmaf(ww.y, h[4 * j4 + 1], acc);
            acc = fmaf(ww.z, h[4 * j4 + 2], acc);
            acc = fmaf(ww.w, h[4 * j4 + 3], acc);
        }
        float v = base[i] + acc + b2[i];
        if (agstore) ag_store(outp + i, v);
        else         outp[i] = v;
    }
}

// ---------------------------------------------------------------------------
// kA: agg1 = agg_W1 . states2 + agg_b1 (27 nodes x 40 blocks x 8 rows),
// then per-node last block runs the node's update MLP -> ns1[node].
__global__ void __launch_bounds__(256) kA(
    const float* __restrict__ W,        // agg_W1 [8640][8640] block rows
    const float* __restrict__ x,        // states2 [27][8640]
    const float* __restrict__ bias,     // agg_b1 [8640]
    const float* __restrict__ states1,  // [27][320]
    const float* __restrict__ W1,       // up_W1_1 [27][64][640]
    const float* __restrict__ b1,       // [27][64]
    const float* __restrict__ W2,       // up_W2_1 [27][320][64]
    const float* __restrict__ b2,       // [27][320]
    float* __restrict__ agg1,           // ws [8640]
    float* __restrict__ ns1,            // ws [8640]
    int*   __restrict__ cnt)            // ws [27], zeroed per replay
{
    __shared__ __align__(16) float comb[640];
    __shared__ float h[64];
    __shared__ float red[4][8];
    __shared__ int last;

    const int b    = blockIdx.x;
    const int node = b / 40;
    const int row0 = node * 320 + (b % 40) * 8;
    const int tid  = threadIdx.x;
    const int wv   = tid >> 6, lane = tid & 63;

    // --- column-parallel 8-row GEMV (R5 structure) ---
    {
        const float4* __restrict__ xf = reinterpret_cast<const float4*>(x) + (size_t)node * 2160;
        const float4* __restrict__ Wb = reinterpret_cast<const float4*>(W);
        float4 acc[8];
        #pragma unroll
        for (int r = 0; r < 8; ++r) acc[r] = make_float4(0.f, 0.f, 0.f, 0.f);
        for (int j = tid; j < 2160; j += 256) {
            float4 xv = xf[j];
            #pragma unroll
            for (int r = 0; r < 8; ++r) {
                float4 w = Wb[(size_t)(row0 + r) * 2160 + j];
                acc[r].x = fmaf(w.x, xv.x, acc[r].x);
                acc[r].y = fmaf(w.y, xv.y, acc[r].y);
                acc[r].z = fmaf(w.z, xv.z, acc[r].z);
                acc[r].w = fmaf(w.w, xv.w, acc[r].w);
            }
        }
        #pragma unroll
        for (int r = 0; r < 8; ++r) {
            float s = (acc[r].x + acc[r].y) + (acc[r].z + acc[r].w);
            s = wave_reduce_sum(s);
            if (lane == 0) red[wv][r] = s;
        }
        __syncthreads();
        if (tid < 8) {
            float v = red[0][tid] + red[1][tid] + red[2][tid] + red[3][tid];
            ag_store(agg1 + row0 + tid, v + bias[row0 + tid]);
        }
    }

    // --- rendezvous (R3-proven: drain via barrier, relaxed agent counter) ---
    __syncthreads();
    if (tid == 0)
        last = __hip_atomic_fetch_add(&cnt[node], 1,
                                      __ATOMIC_RELAXED, __HIP_MEMORY_SCOPE_AGENT);
    __syncthreads();
    if (last != 39) return;

    // --- node MLP tail ---
    for (int j = tid; j < 320; j += 256) {
        comb[j]       = states1[node * 320 + j];
        comb[320 + j] = ag_load(agg1 + node * 320 + j);
    }
    mlp_core(tid,
             W1 + (size_t)node * 64 * 640, b1 + node * 64,
             W2 + (size_t)node * 320 * 64, b2 + node * 320,
             comb /*residual = states1 staged in comb[0:320]*/,
             ns1 + node * 320, comb, h, /*agstore=*/false);  // kernel boundary covers kB
}

// ---------------------------------------------------------------------------
// kB: agg0 partials (4 col-slices x 80 blocks x 4 rows) over agg_W0 . ns1,
// then the 320th block sums partials and runs the root MLP -> out.
__global__ void __launch_bounds__(256) kB(
    const float* __restrict__ W,        // agg_W0 [320][8640]
    const float* __restrict__ ns1,      // ws [8640] (coherent via kernel boundary)
    const float* __restrict__ aggb0,    // [320]
    const float* __restrict__ state0,   // [320]
    const float* __restrict__ ext,      // [320]
    const float* __restrict__ W1,       // up_W1_0 [64][640]
    const float* __restrict__ b1,       // [64]
    const float* __restrict__ W2,       // up_W2_0 [320][64]
    const float* __restrict__ b2,       // [320]
    float* __restrict__ agg0p,          // ws [4][320]
    float* __restrict__ out,            // d_out [320]
    int*   __restrict__ cnt)            // ws [1], zeroed per replay
{
    __shared__ __align__(16) float comb[640];
    __shared__ float h[64];
    __shared__ float red[4][4];
    __shared__ int last;

    const int b   = blockIdx.x;     // 0..319
    const int cs  = b / 80;
    const int r0  = (b % 80) * 4;
    const int tid = threadIdx.x;
    const int wv  = tid >> 6, lane = tid & 63;

    {
        const float4* __restrict__ xf = reinterpret_cast<const float4*>(ns1);
        const float4* __restrict__ Wb = reinterpret_cast<const float4*>(W);
        float a0 = 0.f, a1 = 0.f, a2 = 0.f, a3 = 0.f;
        const int jend = cs * 540 + 540;
        for (int j = cs * 540 + tid; j < jend; j += 256) {
            float4 xv = xf[j];
            float4 w0 = Wb[(size_t)(r0 + 0) * 2160 + j];
            float4 w1 = Wb[(size_t)(r0 + 1) * 2160 + j];
            float4 w2 = Wb[(size_t)(r0 + 2) * 2160 + j];
            float4 w3 = Wb[(size_t)(r0 + 3) * 2160 + j];
            a0 = fmaf(w0.x, xv.x, fmaf(w0.y, xv.y, fmaf(w0.z, xv.z, fmaf(w0.w, xv.w, a0))));
            a1 = fmaf(w1.x, xv.x, fmaf(w1.y, xv.y, fmaf(w1.z, xv.z, fmaf(w1.w, xv.w, a1))));
            a2 = fmaf(w2.x, xv.x, fmaf(w2.y, xv.y, fmaf(w2.z, xv.z, fmaf(w2.w, xv.w, a2))));
            a3 = fmaf(w3.x, xv.x, fmaf(w3.y, xv.y, fmaf(w3.z, xv.z, fmaf(w3.w, xv.w, a3))));
        }
        a0 = wave_reduce_sum(a0);
        a1 = wave_reduce_sum(a1);
        a2 = wave_reduce_sum(a2);
        a3 = wave_reduce_sum(a3);
        if (lane == 0) { red[wv][0] = a0; red[wv][1] = a1; red[wv][2] = a2; red[wv][3] = a3; }
        __syncthreads();
        if (tid < 4) {
            float v = red[0][tid] + red[1][tid] + red[2][tid] + red[3][tid];
            ag_store(agg0p + cs * 320 + r0 + tid, v);
        }
    }

    __syncthreads();
    if (tid == 0)
        last = __hip_atomic_fetch_add(cnt, 1,
                                      __ATOMIC_RELAXED, __HIP_MEMORY_SCOPE_AGENT);
    __syncthreads();
    if (last != 319) return;

    // --- root MLP tail ---
    for (int j = tid; j < 320; j += 256) {
        comb[j]       = state0[j] + ext[j];
        comb[320 + j] = ag_load(agg0p + j) + ag_load(agg0p + 320 + j)
                      + ag_load(agg0p + 640 + j) + ag_load(agg0p + 960 + j)
                      + aggb0[j];
    }
    mlp_core(tid, W1, b1, W2, b2, comb, out, comb, h, /*agstore=*/false);
}

extern "C" void kernel_launch(void* const* d_in, const int* in_sizes, int n_in,
                              void* d_out, int out_size, void* d_ws, size_t ws_size,
                              hipStream_t stream) {
    const float* ext      = (const float*)d_in[0];
    const float* state0   = (const float*)d_in[1];
    const float* states1  = (const float*)d_in[2];
    const float* states2  = (const float*)d_in[3];
    const float* agg_W0   = (const float*)d_in[4];
    const float* agg_b0   = (const float*)d_in[5];
    const float* agg_W1   = (const float*)d_in[6];
    const float* agg_b1   = (const float*)d_in[7];
    const float* up_W1_0  = (const float*)d_in[8];
    const float* up_b1_0  = (const float*)d_in[9];
    const float* up_W2_0  = (const float*)d_in[10];
    const float* up_b2_0  = (const float*)d_in[11];
    const float* up_W1_1  = (const float*)d_in[12];
    const float* up_b1_1  = (const float*)d_in[13];
    const float* up_W2_1  = (const float*)d_in[14];
    const float* up_b2_1  = (const float*)d_in[15];

    float* out   = (float*)d_out;
    float* ws    = (float*)d_ws;
    float* agg1  = ws;             // 8640
    float* ns1   = ws + 8640;      // 8640
    float* agg0p = ws + 17280;     // 1280
    int*   cnt   = (int*)(ws + 18560); // 27 + 1

    hipMemsetAsync(cnt, 0, 28 * sizeof(int), stream);

    kA<<<1080, 256, 0, stream>>>(agg_W1, states2, agg_b1, states1,
                                 up_W1_1, up_b1_1, up_W2_1, up_b2_1,
                                 agg1, ns1, cnt);
    kB<<<320, 256, 0, stream>>>(agg_W0, ns1, agg_b0, state0, ext,
                                up_W1_0, up_b1_0, up_W2_0, up_b2_0,
                                agg0p, out, cnt + 27);
}

// Round 8
// 95.553 us; speedup vs baseline: 2.4557x; 2.4557x over previous
//
#include <hip/hip_runtime.h>
#include <hip/hip_bf16.h>

// S=64, C=27. DOTLEN = 8640 floats = 2160 float4/row; state = 320; comb = 640; hidden = 64.
// 4-kernel chain, no cross-block sync, kernel-boundary coherence only.

__device__ __forceinline__ float wave_reduce_sum(float v) {
    v += __shfl_xor(v, 32, 64);
    v += __shfl_xor(v, 16, 64);
    v += __shfl_xor(v, 8, 64);
    v += __shfl_xor(v, 4, 64);
    v += __shfl_xor(v, 2, 64);
    v += __shfl_xor(v, 1, 64);
    return v;
}

__device__ __forceinline__ float fma4s(float4 w, float4 x, float acc) {
    acc = fmaf(w.x, x.x, acc);
    acc = fmaf(w.y, x.y, acc);
    acc = fmaf(w.z, x.z, acc);
    acc = fmaf(w.w, x.w, acc);
    return acc;
}

__device__ __forceinline__ float4 add4(float4 a, float4 b) {
    return make_float4(a.x + b.x, a.y + b.y, a.z + b.z, a.w + b.w);
}

// ---------------------------------------------------------------------------
// k1: agg1[8640] = agg_W1 . states2 + agg_b1. (R5 structure, unchanged)
// 8 rows/block, column-parallel. Grid 27 nodes x 40 row-blocks = 1080.
__global__ void __launch_bounds__(256) k1_gemv(
    const float* __restrict__ W,     // [8640][8640] block-diag rows
    const float* __restrict__ x,     // [27][8640]
    const float* __restrict__ bias,  // [8640]
    float*       __restrict__ y)     // [8640]
{
    const int b    = blockIdx.x;
    const int node = b / 40;
    const int row0 = node * 320 + (b % 40) * 8;
    const int tid  = threadIdx.x;

    const float4* __restrict__ xf = reinterpret_cast<const float4*>(x) + (size_t)node * 2160;
    const float4* wp[8];
    #pragma unroll
    for (int r = 0; r < 8; ++r)
        wp[r] = reinterpret_cast<const float4*>(W) + (size_t)(row0 + r) * 2160;

    float4 acc[8];
    #pragma unroll
    for (int r = 0; r < 8; ++r) acc[r] = make_float4(0.f, 0.f, 0.f, 0.f);

    for (int j = tid; j < 2160; j += 256) {
        float4 xv = xf[j];
        #pragma unroll
        for (int r = 0; r < 8; ++r) {
            float4 w = wp[r][j];
            acc[r].x = fmaf(w.x, xv.x, acc[r].x);
            acc[r].y = fmaf(w.y, xv.y, acc[r].y);
            acc[r].z = fmaf(w.z, xv.z, acc[r].z);
            acc[r].w = fmaf(w.w, xv.w, acc[r].w);
        }
    }

    float s[8];
    #pragma unroll
    for (int r = 0; r < 8; ++r) {
        s[r] = (acc[r].x + acc[r].y) + (acc[r].z + acc[r].w);
        s[r] = wave_reduce_sum(s[r]);
    }

    __shared__ float red[4][8];
    const int wv = tid >> 6, lane = tid & 63;
    if (lane == 0) {
        #pragma unroll
        for (int r = 0; r < 8; ++r) red[wv][r] = s[r];
    }
    __syncthreads();
    if (tid < 8) {
        float v = red[0][tid] + red[1][tid] + red[2][tid] + red[3][tid];
        y[row0 + tid] = v + bias[row0 + tid];
    }
}

// ---------------------------------------------------------------------------
// k2: full per-node MLP (h1 + ns1) in one kernel. 27 blocks x 512 threads.
// ns1[n][i] = states1[n][i] + W2[n][i,:] @ relu(W1[n] @ [states1[n],agg1[n]] + b1[n]) + b2[n][i]
__global__ void __launch_bounds__(512) k2_mlp(
    const float* __restrict__ states1,  // [27][320]
    const float* __restrict__ agg1,     // [8640] (ws)
    const float* __restrict__ W1,       // [27][64][640]
    const float* __restrict__ b1,       // [27][64]
    const float* __restrict__ W2,       // [27][320][64]
    const float* __restrict__ b2,       // [27][320]
    float*       __restrict__ ns1)      // [8640] (ws)
{
    __shared__ __align__(16) float comb[640];
    __shared__ float h[64];
    const int n   = blockIdx.x;
    const int tid = threadIdx.x;
    const int wv  = tid >> 6, lane = tid & 63;

    float4* combf = reinterpret_cast<float4*>(comb);
    const float4* __restrict__ s1f = reinterpret_cast<const float4*>(states1) + (size_t)n * 80;
    const float4* __restrict__ a1f = reinterpret_cast<const float4*>(agg1) + (size_t)n * 80;
    if (tid < 80)       combf[tid] = s1f[tid];
    else if (tid < 160) combf[tid] = a1f[tid - 80];
    __syncthreads();

    // h: 8 waves x 8 outputs each
    const float4* __restrict__ cf = reinterpret_cast<const float4*>(comb);
    #pragma unroll
    for (int kk = 0; kk < 8; ++kk) {
        const int k = wv * 8 + kk;
        const float4* __restrict__ Wf = reinterpret_cast<const float4*>(W1) + ((size_t)n * 64 + k) * 160;
        float acc = 0.f;
        #pragma unroll
        for (int j = lane; j < 160; j += 64)
            acc = fma4s(Wf[j], cf[j], acc);
        acc = wave_reduce_sum(acc);
        if (lane == 0) h[k] = fmaxf(acc + b1[n * 64 + k], 0.f);
    }
    __syncthreads();

    // ns1: one row per thread (tid < 320)
    if (tid < 320) {
        const float4* __restrict__ w = reinterpret_cast<const float4*>(W2 + ((size_t)n * 320 + tid) * 64);
        float acc = 0.f;
        #pragma unroll
        for (int j4 = 0; j4 < 16; ++j4) {
            float4 ww = w[j4];
            acc = fmaf(ww.x, h[4 * j4 + 0], acc);
            acc = fmaf(ww.y, h[4 * j4 + 1], acc);
            acc = fmaf(ww.z, h[4 * j4 + 2], acc);
            acc = fmaf(ww.w, h[4 * j4 + 3], acc);
        }
        ns1[n * 320 + tid] = states1[n * 320 + tid] + acc + b2[n * 320 + tid];
    }
}

// ---------------------------------------------------------------------------
// k3: agg0 partials: agg0p[cs][320] = agg_W0[:, slice(cs)] @ ns1[slice(cs)].
// (R5 structure, unchanged) 4 col-slices x 80 row-blocks = 320 blocks.
__global__ void __launch_bounds__(256) k3_gemv(
    const float* __restrict__ W,    // [320][8640]
    const float* __restrict__ x,    // ns1 [8640] (ws)
    float*       __restrict__ yp)   // [4][320] partials (ws)
{
    const int b   = blockIdx.x;     // 0..319
    const int cs  = b / 80;
    const int r0  = (b % 80) * 4;
    const int tid = threadIdx.x;

    const float4* __restrict__ xf  = reinterpret_cast<const float4*>(x);
    const float4* __restrict__ w0p = reinterpret_cast<const float4*>(W) + (size_t)(r0 + 0) * 2160;
    const float4* __restrict__ w1p = reinterpret_cast<const float4*>(W) + (size_t)(r0 + 1) * 2160;
    const float4* __restrict__ w2p = reinterpret_cast<const float4*>(W) + (size_t)(r0 + 2) * 2160;
    const float4* __restrict__ w3p = reinterpret_cast<const float4*>(W) + (size_t)(r0 + 3) * 2160;

    float4 a0 = make_float4(0.f, 0.f, 0.f, 0.f), a1 = a0, a2 = a0, a3 = a0;
    const int jend = cs * 540 + 540;
    for (int j = cs * 540 + tid; j < jend; j += 256) {
        float4 xv = xf[j];
        float4 w0 = w0p[j];
        float4 w1 = w1p[j];
        float4 w2 = w2p[j];
        float4 w3 = w3p[j];
        a0.x = fmaf(w0.x, xv.x, a0.x); a0.y = fmaf(w0.y, xv.y, a0.y);
        a0.z = fmaf(w0.z, xv.z, a0.z); a0.w = fmaf(w0.w, xv.w, a0.w);
        a1.x = fmaf(w1.x, xv.x, a1.x); a1.y = fmaf(w1.y, xv.y, a1.y);
        a1.z = fmaf(w1.z, xv.z, a1.z); a1.w = fmaf(w1.w, xv.w, a1.w);
        a2.x = fmaf(w2.x, xv.x, a2.x); a2.y = fmaf(w2.y, xv.y, a2.y);
        a2.z = fmaf(w2.z, xv.z, a2.z); a2.w = fmaf(w2.w, xv.w, a2.w);
        a3.x = fmaf(w3.x, xv.x, a3.x); a3.y = fmaf(w3.y, xv.y, a3.y);
        a3.z = fmaf(w3.z, xv.z, a3.z); a3.w = fmaf(w3.w, xv.w, a3.w);
    }
    float s0 = (a0.x + a0.y) + (a0.z + a0.w);
    float s1 = (a1.x + a1.y) + (a1.z + a1.w);
    float s2 = (a2.x + a2.y) + (a2.z + a2.w);
    float s3 = (a3.x + a3.y) + (a3.z + a3.w);
    s0 = wave_reduce_sum(s0);
    s1 = wave_reduce_sum(s1);
    s2 = wave_reduce_sum(s2);
    s3 = wave_reduce_sum(s3);

    __shared__ float red[4][4];
    const int wv = tid >> 6, lane = tid & 63;
    if (lane == 0) { red[wv][0] = s0; red[wv][1] = s1; red[wv][2] = s2; red[wv][3] = s3; }
    __syncthreads();
    if (tid < 4) {
        yp[cs * 320 + r0 + tid] =
            red[0][tid] + red[1][tid] + red[2][tid] + red[3][tid];
    }
}

// ---------------------------------------------------------------------------
// k4: root MLP in one block x 512 threads.
// out = (state0+ext) + W2 @ relu(W1 @ [state0+ext, sum(agg0p)+agg_b0] + b1) + b2
__global__ void __launch_bounds__(512) k4_root(
    const float* __restrict__ state0,  // [320]
    const float* __restrict__ ext,     // [320]
    const float* __restrict__ agg0p,   // [4][320] (ws)
    const float* __restrict__ aggb0,   // [320]
    const float* __restrict__ W1,      // [64][640]
    const float* __restrict__ b1,      // [64]
    const float* __restrict__ W2,      // [320][64]
    const float* __restrict__ b2,      // [320]
    float*       __restrict__ out)     // [320]
{
    __shared__ __align__(16) float comb[640];
    __shared__ float h[64];
    const int tid = threadIdx.x;
    const int wv  = tid >> 6, lane = tid & 63;

    float4* combf = reinterpret_cast<float4*>(comb);
    const float4* __restrict__ s0f = reinterpret_cast<const float4*>(state0);
    const float4* __restrict__ exf = reinterpret_cast<const float4*>(ext);
    const float4* __restrict__ p0  = reinterpret_cast<const float4*>(agg0p);
    const float4* __restrict__ b0f = reinterpret_cast<const float4*>(aggb0);
    if (tid < 80) {
        combf[tid] = add4(s0f[tid], exf[tid]);
    } else if (tid < 160) {
        int jj = tid - 80;
        combf[tid] = add4(add4(add4(p0[jj], p0[80 + jj]), add4(p0[160 + jj], p0[240 + jj])), b0f[jj]);
    }
    __syncthreads();

    const float4* __restrict__ cf = reinterpret_cast<const float4*>(comb);
    #pragma unroll
    for (int kk = 0; kk < 8; ++kk) {
        const int k = wv * 8 + kk;
        const float4* __restrict__ Wf = reinterpret_cast<const float4*>(W1) + (size_t)k * 160;
        float acc = 0.f;
        #pragma unroll
        for (int j = lane; j < 160; j += 64)
            acc = fma4s(Wf[j], cf[j], acc);
        acc = wave_reduce_sum(acc);
        if (lane == 0) h[k] = fmaxf(acc + b1[k], 0.f);
    }
    __syncthreads();

    if (tid < 320) {
        const float4* __restrict__ w = reinterpret_cast<const float4*>(W2 + (size_t)tid * 64);
        float acc = 0.f;
        #pragma unroll
        for (int j4 = 0; j4 < 16; ++j4) {
            float4 ww = w[j4];
            acc = fmaf(ww.x, h[4 * j4 + 0], acc);
            acc = fmaf(ww.y, h[4 * j4 + 1], acc);
            acc = fmaf(ww.z, h[4 * j4 + 2], acc);
            acc = fmaf(ww.w, h[4 * j4 + 3], acc);
        }
        out[tid] = comb[tid] + acc + b2[tid];
    }
}

extern "C" void kernel_launch(void* const* d_in, const int* in_sizes, int n_in,
                              void* d_out, int out_size, void* d_ws, size_t ws_size,
                              hipStream_t stream) {
    const float* ext      = (const float*)d_in[0];
    const float* state0   = (const float*)d_in[1];
    const float* states1  = (const float*)d_in[2];
    const float* states2  = (const float*)d_in[3];
    const float* agg_W0   = (const float*)d_in[4];
    const float* agg_b0   = (const float*)d_in[5];
    const float* agg_W1   = (const float*)d_in[6];
    const float* agg_b1   = (const float*)d_in[7];
    const float* up_W1_0  = (const float*)d_in[8];
    const float* up_b1_0  = (const float*)d_in[9];
    const float* up_W2_0  = (const float*)d_in[10];
    const float* up_b2_0  = (const float*)d_in[11];
    const float* up_W1_1  = (const float*)d_in[12];
    const float* up_b1_1  = (const float*)d_in[13];
    const float* up_W2_1  = (const float*)d_in[14];
    const float* up_b2_1  = (const float*)d_in[15];

    float* out   = (float*)d_out;
    float* ws    = (float*)d_ws;
    float* agg1  = ws;             // 8640
    float* ns1   = ws + 8640;      // 8640
    float* agg0p = ws + 17280;     // 1280

    k1_gemv<<<1080, 256, 0, stream>>>(agg_W1, states2, agg_b1, agg1);
    k2_mlp <<<27,   512, 0, stream>>>(states1, agg1, up_W1_1, up_b1_1, up_W2_1, up_b2_1, ns1);
    k3_gemv<<<320,  256, 0, stream>>>(agg_W0, ns1, agg0p);
    k4_root<<<1,    512, 0, stream>>>(state0, ext, agg0p, agg_b0, up_W1_0, up_b1_0, up_W2_0, up_b2_0, out);
}